// Round 11
// baseline (728.106 us; speedup 1.0000x reference)
//
#include <hip/hip_runtime.h>

// 2-layer LSTM (H=64, D=1), N=2048, T=512 — MFMA bf16 3-term split precision.
// R11: ANTI-PHASE pipeline. 128 blocks x 512 threads (8 waves, 2/SIMD).
// Each step = 2 barrier phases with E and O in OPPOSITE roles:
//   Phase A: E = ds_read + 12 MFMA (matrix pipe) | O = cell+write h2(m-2)+dot (VALU)
//   Phase B: E = cell + write h1(m) (VALU)       | O = ds_read + 24 MFMA (matrix)
// -> complementary pipe usage every phase; O's acc carries in REGISTERS
// across the barrier (no LDS round-trip, unlike R8). h2 lags h1 by 2 steps.
// Planes double-buffered by parity; ring flush on E in phase A.

typedef __attribute__((ext_vector_type(8))) short short8;
typedef __attribute__((ext_vector_type(4))) float f32x4;

#define NT 512
#define XPITCH 2060              // 515 words (odd) -> conflict-free x reads
#define XP 0                     // 16 * 2060 = 32960
#define HP 32960                 // 8 planes * 2304 = 18432
#define RING 51392               // 128 slots * 256 B (4 ow x 16 s x f32)
#define LDS_BYTES 84160
// plane(layer 0=h1/1=h2, buf 0/1, hl): [16 s][144 B], row j at byte s*144+2j
#define PLANE(layer, buf, hl) (HP + ((((layer) * 2 + (buf)) * 2) + (hl)) * 2304)

__device__ __forceinline__ float fast_rcp(float x) { return __builtin_amdgcn_rcpf(x); }
__device__ __forceinline__ unsigned short bf_rne(float f) {
  unsigned u = __float_as_uint(f);
  return (unsigned short)((u + 0x7FFFu + ((u >> 16) & 1u)) >> 16);
}
__device__ __forceinline__ void split8(const float* p, short8& hi, short8& lo) {
#pragma unroll
  for (int e = 0; e < 8; ++e) {
    float v = p[e];
    unsigned short h = bf_rne(v);
    float hf = __uint_as_float(((unsigned)h) << 16);
    hi[e] = (short)h;
    lo[e] = (short)bf_rne(v - hf);
  }
}
__device__ __forceinline__ unsigned cvt_pk(float a, float b) {
  unsigned r;
  asm("v_cvt_pk_bf16_f32 %0, %1, %2" : "=v"(r) : "v"(a), "v"(b));
  return r;
}
__device__ __forceinline__ f32x4 mfma16(short8 a, short8 b, f32x4 c) {
  return __builtin_amdgcn_mfma_f32_16x16x32_bf16(a, b, c, 0, 0, 0);
}
// (c,h) update from 4 gate pre-activations: 5 exp + 3 rcp.
__device__ __forceinline__ void cell(float i, float f, float gg, float o,
                                     float& c, float& h) {
  const float ei = __expf(-i), ef = __expf(-f), eg = __expf(-2.f * gg),
              eo = __expf(-o);
  const float P = (1.f - eg) * fast_rcp((1.f + ei) * (1.f + eg));
  c = fmaf(c, fast_rcp(1.f + ef), P);
  const float cc = fminf(15.f, fmaxf(-15.f, c));
  const float ec = __expf(-2.f * cc);
  h = (1.f - ec) * fast_rcp((1.f + eo) * (1.f + ec));
}
// Raw barrier: only LDS drained (lgkmcnt); global flush stores fly.
__device__ __forceinline__ void fast_barrier() {
  __builtin_amdgcn_sched_barrier(0);
  asm volatile("s_waitcnt lgkmcnt(0)" ::: "memory");
  __builtin_amdgcn_s_barrier();
  asm volatile("" ::: "memory");
  __builtin_amdgcn_sched_barrier(0);
}

__global__ __launch_bounds__(512, 2) void lstm2_r11(
    const float* __restrict__ y, const float* __restrict__ Wih1,
    const float* __restrict__ Whh1, const float* __restrict__ bih1,
    const float* __restrict__ bhh1, const float* __restrict__ Wih2,
    const float* __restrict__ Whh2, const float* __restrict__ bih2,
    const float* __restrict__ bhh2, const float* __restrict__ Wlin,
    const float* __restrict__ blin, float* __restrict__ out) {
  extern __shared__ char smem[];
  const int tid = threadIdx.x;
  const int w = tid >> 6;          // wave 0..7
  const int lane = tid & 63;
  const int g = lane >> 4;
  const int s = lane & 15;
  const int s0 = blockIdx.x * 16;

  // ---- stage x: XP[ss][t] ----
  for (int i = tid; i < 16 * 512; i += 512) {
    const int ss = i >> 9, t = i & 511;
    *(float*)(smem + XP + ss * XPITCH + t * 4) = y[(size_t)(s0 + ss) * 512 + t];
  }
  // ---- zero all 8 h planes ----
  for (int i = tid; i < 18432 / 4; i += 512) *(float*)(smem + HP + i * 4) = 0.f;
  const float bl0 = blin[0];
  __syncthreads();  // full barrier once (drains staging)

  const int bo0 = s * 144 + 16 * g, bo1 = bo0 + 64;

  if (w < 4) {
    // ============ E: phase A = read+MFMA for h1(m); phase B = cell+write ====
    short8 a1h[4][2], a1l[4][2];
#pragma unroll
    for (int p = 0; p < 4; ++p)
#pragma unroll
      for (int c = 0; c < 2; ++c)
        split8(Whh1 + (size_t)(p * 64 + 16 * w + s) * 64 + 32 * c + 8 * g,
               a1h[p][c], a1l[p][c]);
    float bias1c[4][4], wih1c[4][4];
#pragma unroll
    for (int p = 0; p < 4; ++p)
#pragma unroll
      for (int r = 0; r < 4; ++r) {
        const int row = p * 64 + 16 * w + 4 * g + r;
        bias1c[p][r] = bih1[row] + bhh1[row];
        wih1c[p][r] = Wih1[row];
      }
    float c1[4] = {0.f, 0.f, 0.f, 0.f};
    const int hwr0 = s * 144 + 32 * w + 8 * g;
    float xnext = *(const float*)(smem + XP + s * XPITCH);
    f32x4 acc[4], acx[4];

#pragma unroll 1
    for (int m = 0; m <= NT + 1; ++m) {
      // ---------------- phase A: ring flush + MFMA ----------------
      if (m >= 68 && (m & 63) == 4) {  // flush ring pos [m-68, m-5]
        const int thr = w * 64 + lane;
        const int s2 = thr >> 4, iq = thr & 15;
        const int f0 = m - 68;
        float* ob = out + (size_t)(s0 + s2) * 511;
#pragma unroll
        for (int u = 0; u < 4; ++u) {
          const int p = f0 + iq * 4 + u;
          const char* op = smem + RING + (p & 127) * 256 + s2 * 4;
          ob[p] = *(const float*)(op) + *(const float*)(op + 64) +
                  *(const float*)(op + 128) + *(const float*)(op + 192) + bl0;
        }
      }
      if (m < NT) {
        const float x = xnext;
        const int nk = (m + 1 < NT) ? m + 1 : NT - 1;
        xnext = *(const float*)(smem + XP + s * XPITCH + nk * 4);  // prefetch
        const int rp0 = PLANE(0, (m - 1) & 1, 0), rp1 = PLANE(0, (m - 1) & 1, 1);
        const short8 Bh0 = *(const short8*)(smem + rp0 + bo0);
        const short8 Bl0 = *(const short8*)(smem + rp1 + bo0);
        const short8 Bh1 = *(const short8*)(smem + rp0 + bo1);
        const short8 Bl1 = *(const short8*)(smem + rp1 + bo1);
#pragma unroll
        for (int p = 0; p < 4; ++p) {
#pragma unroll
          for (int r = 0; r < 4; ++r) acc[p][r] = fmaf(wih1c[p][r], x, bias1c[p][r]);
          acx[p] = (f32x4){0.f, 0.f, 0.f, 0.f};
        }
        __builtin_amdgcn_s_setprio(1);
#pragma unroll
        for (int p = 0; p < 4; ++p) acc[p] = mfma16(a1h[p][0], Bh0, acc[p]);
#pragma unroll
        for (int p = 0; p < 4; ++p) acx[p] = mfma16(a1h[p][1], Bh1, acx[p]);
#pragma unroll
        for (int p = 0; p < 4; ++p) acc[p] = mfma16(a1h[p][0], Bl0, acc[p]);
#pragma unroll
        for (int p = 0; p < 4; ++p) acx[p] = mfma16(a1h[p][1], Bl1, acx[p]);
#pragma unroll
        for (int p = 0; p < 4; ++p) acc[p] = mfma16(a1l[p][0], Bh0, acc[p]);
#pragma unroll
        for (int p = 0; p < 4; ++p) acx[p] = mfma16(a1l[p][1], Bh1, acx[p]);
        __builtin_amdgcn_s_setprio(0);
      }
      fast_barrier();
      // ---------------- phase B: cell + write h1(m) ----------------
      if (m < NT) {
#pragma unroll
        for (int p = 0; p < 4; ++p) acc[p] += acx[p];
        float h1n[4];
#pragma unroll
        for (int r = 0; r < 4; ++r)
          cell(acc[0][r], acc[1][r], acc[2][r], acc[3][r], c1[r], h1n[r]);
        const unsigned hA = cvt_pk(h1n[0], h1n[1]), hB = cvt_pk(h1n[2], h1n[3]);
        const unsigned lA = cvt_pk(h1n[0] - __uint_as_float(hA << 16),
                                   h1n[1] - __uint_as_float(hA & 0xFFFF0000u));
        const unsigned lB = cvt_pk(h1n[2] - __uint_as_float(hB << 16),
                                   h1n[3] - __uint_as_float(hB & 0xFFFF0000u));
        *(uint2*)(smem + PLANE(0, m & 1, 0) + hwr0) = make_uint2(hA, hB);
        *(uint2*)(smem + PLANE(0, m & 1, 1) + hwr0) = make_uint2(lA, lB);
      }
      fast_barrier();
    }
    __syncthreads();
    // ---- tail flush: positions 448..510 ----
    {
      const int thr = w * 64 + lane;
      for (int e = thr; e < 63 * 16; e += 256) {
        const int s2 = e & 15, off = e >> 4;
        const int p = 448 + off;
        const char* op = smem + RING + (p & 127) * 256 + s2 * 4;
        out[(size_t)(s0 + s2) * 511 + p] =
            *(const float*)(op) + *(const float*)(op + 64) +
            *(const float*)(op + 128) + *(const float*)(op + 192) + bl0;
      }
    }
  } else {
    // ============ O: phase A = cell+write h2(m-2)+dot; phase B = read+MFMA ==
    const int ow = w - 4;
    short8 a2h[4][4], a2l[4][4];  // c: 0,1 = Wih2 halves; 2,3 = Whh2 halves
#pragma unroll
    for (int p = 0; p < 4; ++p)
#pragma unroll
      for (int c = 0; c < 4; ++c) {
        const float* src = (c < 2) ? (Wih2 + (size_t)(p * 64 + 16 * ow + s) * 64 + 32 * c + 8 * g)
                                   : (Whh2 + (size_t)(p * 64 + 16 * ow + s) * 64 + 32 * (c - 2) + 8 * g);
        split8(src, a2h[p][c], a2l[p][c]);
      }
    float bias2c[4][4], wlinc[4];
#pragma unroll
    for (int p = 0; p < 4; ++p)
#pragma unroll
      for (int r = 0; r < 4; ++r)
        bias2c[p][r] = bih2[p * 64 + 16 * ow + 4 * g + r] +
                       bhh2[p * 64 + 16 * ow + 4 * g + r];
#pragma unroll
    for (int r = 0; r < 4; ++r) wlinc[r] = Wlin[16 * ow + 4 * g + r];
    float c2[4] = {0.f, 0.f, 0.f, 0.f};
    const int hwr0 = s * 144 + 32 * ow + 8 * g;
    f32x4 acc[4], acx[4];

#pragma unroll 1
    for (int m = 0; m <= NT + 1; ++m) {
      // -------- phase A: cell acc2(m-2) -> h2(m-2), write plane, dot --------
      if (m >= 2) {
#pragma unroll
        for (int p = 0; p < 4; ++p) acc[p] += acx[p];
        float h2n[4];
#pragma unroll
        for (int r = 0; r < 4; ++r)
          cell(acc[0][r], acc[1][r], acc[2][r], acc[3][r], c2[r], h2n[r]);
        const unsigned hA = cvt_pk(h2n[0], h2n[1]), hB = cvt_pk(h2n[2], h2n[3]);
        const unsigned lA = cvt_pk(h2n[0] - __uint_as_float(hA << 16),
                                   h2n[1] - __uint_as_float(hA & 0xFFFF0000u));
        const unsigned lB = cvt_pk(h2n[2] - __uint_as_float(hB << 16),
                                   h2n[3] - __uint_as_float(hB & 0xFFFF0000u));
        *(uint2*)(smem + PLANE(1, m & 1, 0) + hwr0) = make_uint2(hA, hB);
        *(uint2*)(smem + PLANE(1, m & 1, 1) + hwr0) = make_uint2(lA, lB);
        if (m >= 3) {  // dot(h2(m-2)) -> ring pos m-3 (out col j-1 for j=m-2)
          float pw = wlinc[0] * h2n[0];
          pw = fmaf(wlinc[1], h2n[1], pw);
          pw = fmaf(wlinc[2], h2n[2], pw);
          pw = fmaf(wlinc[3], h2n[3], pw);
          pw += __shfl_xor(pw, 16, 64);
          pw += __shfl_xor(pw, 32, 64);
          if (g == 0)
            *(float*)(smem + RING + ((m - 3) & 127) * 256 + ow * 64 + s * 4) = pw;
        }
      }
      fast_barrier();
      // -------- phase B: read h1(m-1), h2(m-2) frags; 24 MFMA -> acc2(m-1) --
      if (m >= 1 && m <= NT) {
        const int rp0 = PLANE(0, (m - 1) & 1, 0), rp1 = PLANE(0, (m - 1) & 1, 1); // h1(m-1)
        const int rq0 = PLANE(1, m & 1, 0), rq1 = PLANE(1, m & 1, 1);             // h2(m-2)
        const short8 Bh0 = *(const short8*)(smem + rp0 + bo0);
        const short8 Bl0 = *(const short8*)(smem + rp1 + bo0);
        const short8 Bh1 = *(const short8*)(smem + rp0 + bo1);
        const short8 Bl1 = *(const short8*)(smem + rp1 + bo1);
        const short8 Ch0 = *(const short8*)(smem + rq0 + bo0);
        const short8 Cl0 = *(const short8*)(smem + rq1 + bo0);
        const short8 Ch1 = *(const short8*)(smem + rq0 + bo1);
        const short8 Cl1 = *(const short8*)(smem + rq1 + bo1);
#pragma unroll
        for (int p = 0; p < 4; ++p) {
          acc[p] = (f32x4){bias2c[p][0], bias2c[p][1], bias2c[p][2], bias2c[p][3]};
          acx[p] = (f32x4){0.f, 0.f, 0.f, 0.f};
        }
        __builtin_amdgcn_s_setprio(1);
#pragma unroll
        for (int p = 0; p < 4; ++p) acc[p] = mfma16(a2h[p][0], Bh0, acc[p]);
#pragma unroll
        for (int p = 0; p < 4; ++p) acx[p] = mfma16(a2h[p][1], Bh1, acx[p]);
#pragma unroll
        for (int p = 0; p < 4; ++p) acc[p] = mfma16(a2h[p][0], Bl0, acc[p]);
#pragma unroll
        for (int p = 0; p < 4; ++p) acx[p] = mfma16(a2h[p][1], Bl1, acx[p]);
#pragma unroll
        for (int p = 0; p < 4; ++p) acc[p] = mfma16(a2l[p][0], Bh0, acc[p]);
#pragma unroll
        for (int p = 0; p < 4; ++p) acx[p] = mfma16(a2l[p][1], Bh1, acx[p]);
#pragma unroll
        for (int p = 0; p < 4; ++p) acc[p] = mfma16(a2h[p][2], Ch0, acc[p]);
#pragma unroll
        for (int p = 0; p < 4; ++p) acx[p] = mfma16(a2h[p][3], Ch1, acx[p]);
#pragma unroll
        for (int p = 0; p < 4; ++p) acc[p] = mfma16(a2h[p][2], Cl0, acc[p]);
#pragma unroll
        for (int p = 0; p < 4; ++p) acx[p] = mfma16(a2h[p][3], Cl1, acx[p]);
#pragma unroll
        for (int p = 0; p < 4; ++p) acc[p] = mfma16(a2l[p][2], Ch0, acc[p]);
#pragma unroll
        for (int p = 0; p < 4; ++p) acx[p] = mfma16(a2l[p][3], Ch1, acx[p]);
        __builtin_amdgcn_s_setprio(0);
      }
      fast_barrier();
    }
    __syncthreads();
    // E does the tail flush.
  }
}

extern "C" void kernel_launch(void* const* d_in, const int* in_sizes, int n_in,
                              void* d_out, int out_size, void* d_ws, size_t ws_size,
                              hipStream_t stream) {
  const float* y    = (const float*)d_in[0];
  const float* Wih1 = (const float*)d_in[1];
  const float* Whh1 = (const float*)d_in[2];
  const float* bih1 = (const float*)d_in[3];
  const float* bhh1 = (const float*)d_in[4];
  const float* Wih2 = (const float*)d_in[5];
  const float* Whh2 = (const float*)d_in[6];
  const float* bih2 = (const float*)d_in[7];
  const float* bhh2 = (const float*)d_in[8];
  const float* Wlin = (const float*)d_in[9];
  const float* blin = (const float*)d_in[10];
  float* out = (float*)d_out;

  hipFuncSetAttribute((const void*)lstm2_r11,
                      hipFuncAttributeMaxDynamicSharedMemorySize, LDS_BYTES);
  lstm2_r11<<<dim3(128), dim3(512), LDS_BYTES, stream>>>(
      y, Wih1, Whh1, bih1, bhh1, Wih2, Whh2, bih2, bhh2, Wlin, blin, out);
}